// Round 3
// baseline (385.703 us; speedup 1.0000x reference)
//
#include <hip/hip_runtime.h>

typedef unsigned short u16;
typedef unsigned int u32;

typedef __bf16 bf16x8 __attribute__((ext_vector_type(8)));
typedef _Float16 f16x8 __attribute__((ext_vector_type(8)));
typedef float f32x4 __attribute__((ext_vector_type(4)));

typedef __attribute__((address_space(1))) u32 as1_u32;
typedef __attribute__((address_space(3))) u32 as3_u32;

#define EKF 0.18033688011112042f  // 0.125 * log2(e), folded into Q at GEMM1

__device__ __forceinline__ u16 f2bf(float x) {
  u32 u = __float_as_uint(x);
  u = u + 0x7fffu + ((u >> 16) & 1u);   // RNE
  return (u16)(u >> 16);
}
__device__ __forceinline__ u32 pack2(float a, float b) {
  return (u32)f2bf(a) | ((u32)f2bf(b) << 16);
}
__device__ __forceinline__ u32 pkf16(float a, float b) {
  return __builtin_bit_cast(u32, __builtin_amdgcn_cvt_pkrtz(a, b));
}
__device__ __forceinline__ u16 f2h(float a) {
  return (u16)(pkf16(a, a) & 0xffffu);
}
__device__ __forceinline__ void gld_lds16(const u16* g, const u16* l) {
  __builtin_amdgcn_global_load_lds((const as1_u32*)g, (as3_u32*)l, 16, 0, 0);
}
// device-scope (agent) data movement for cross-XCD partial exchange
__device__ __forceinline__ void stg_f32(float* p, float v) {
  __hip_atomic_store(p, v, __ATOMIC_RELAXED, __HIP_MEMORY_SCOPE_AGENT);
}
__device__ __forceinline__ float ldg_f32(const float* p) {
  return __hip_atomic_load(p, __ATOMIC_RELAXED, __HIP_MEMORY_SCOPE_AGENT);
}

// ---------------- fused prepass: x cast + weight transposes + split-counter zero ----
__global__ __launch_bounds__(256) void prepass_kernel(const float* __restrict__ x,
                                                      const float* __restrict__ w_qkv,
                                                      const float* __restrict__ w_out,
                                                      u16* __restrict__ xb,
                                                      u16* __restrict__ wqkvT,
                                                      u16* __restrict__ woutT,
                                                      u32* __restrict__ cnt) {
  __shared__ float tile[64][65];
  int bid = blockIdx.x;
  int t = threadIdx.x;
  if (bid >= 5120) {  // zero the 512 rendezvous counters (every replay)
    if (t < 512) __hip_atomic_store(cnt + t, 0u, __ATOMIC_RELAXED, __HIP_MEMORY_SCOPE_AGENT);
    return;
  }
  if (bid < 4096) {
    int i = bid * 256 + t;
    float4 v = ((const float4*)x)[i];
    uint2 r;
    r.x = pack2(v.x, v.y);
    r.y = pack2(v.z, v.w);
    ((uint2*)xb)[i] = r;
    return;
  }
  const float* W;
  u16* WT;
  int K, N, bx, by;
  if (bid < 4096 + 768) {
    int b2 = bid - 4096;
    W = w_qkv; WT = wqkvT; K = 1024; N = 3072; bx = b2 & 15; by = b2 >> 4;
  } else {
    int b2 = bid - 4864;
    W = w_out; WT = woutT; K = 1024; N = 1024; bx = b2 & 15; by = b2 >> 4;
  }
  int k0 = bx * 64, n0 = by * 64;
  int r = t >> 4, c4 = (t & 15) * 4;
#pragma unroll
  for (int i = 0; i < 4; ++i) {
    int row = r + i * 16;
    float4 v = *(const float4*)&W[(size_t)(k0 + row) * N + n0 + c4];
    tile[row][c4 + 0] = v.x; tile[row][c4 + 1] = v.y;
    tile[row][c4 + 2] = v.z; tile[row][c4 + 3] = v.w;
  }
  __syncthreads();
#pragma unroll
  for (int i = 0; i < 4; ++i) {
    int n = r + i * 16;
    uint2 o;
    o.x = pack2(tile[c4 + 0][n], tile[c4 + 1][n]);
    o.y = pack2(tile[c4 + 2][n], tile[c4 + 3][n]);
    *(uint2*)&WT[(size_t)(n0 + n) * K + k0 + c4] = o;
  }
}

// ---------------- 256x256 8-phase QKV GEMM (unchanged from R1) ----------------
__global__ __launch_bounds__(512, 2) void gemm_qkv256_kernel(const u16* __restrict__ A,
                                                             const u16* __restrict__ BT,
                                                             u16* __restrict__ QK,
                                                             u16* __restrict__ VT) {
  __shared__ __attribute__((aligned(16))) u16 smem[65536];  // 128 KiB -> 1 block/CU
  const int tid = threadIdx.x;
  const int wave = tid >> 6;
  const int lane = tid & 63;
  const int lr = lane & 15;
  const int kg = lane >> 4;
  const int l7 = lr & 7;
  const int wr = wave >> 2;   // 0..1 : M half
  const int wc = wave & 3;    // 0..3 : N quarter

  int b = blockIdx.x;
  int sw = (b & 7) * 24 + (b >> 3);
  const int bn = (sw % 12) * 256;
  const int bm = (sw / 12) * 256;

  const int srow = tid >> 3;
  const int scg = ((tid & 7) ^ (srow & 7)) * 8;  // swizzled source col (u16)
  const u16* pa = A + (size_t)(bm + srow) * 1024 + scg;
  const u16* pb = BT + (size_t)(bn + srow) * 1024 + scg;
  const u32 lw = (u32)wave * 512;

  f32x4 acc[8][4];
#pragma unroll
  for (int i = 0; i < 8; ++i)
#pragma unroll
    for (int j = 0; j < 4; ++j) {
      f32x4 z = {0.f, 0.f, 0.f, 0.f};
      acc[i][j] = z;
    }

  {
    u16* dA = (u16*)smem;
    u16* dB = (u16*)smem + 16384;
#pragma unroll
    for (int i = 0; i < 4; ++i) gld_lds16(pa + (size_t)(i * 64) * 1024, dA + lw + i * 4096);
#pragma unroll
    for (int i = 0; i < 4; ++i) gld_lds16(pb + (size_t)(i * 64) * 1024, dB + lw + i * 4096);
  }

  for (int t = 0; t < 16; ++t) {
    __syncthreads();
    const u16* bA = smem + (t & 1) * 32768;
    const u16* bB = bA + 16384;
    if (t + 1 < 16) {
      u16* dA = (u16*)smem + ((t + 1) & 1) * 32768;
      u16* dB = dA + 16384;
      const int k1 = (t + 1) * 64;
#pragma unroll
      for (int i = 0; i < 4; ++i) gld_lds16(pa + (size_t)(i * 64) * 1024 + k1, dA + lw + i * 4096);
#pragma unroll
      for (int i = 0; i < 4; ++i) gld_lds16(pb + (size_t)(i * 64) * 1024 + k1, dB + lw + i * 4096);
    }
    bf16x8 bfr[2][4];
#pragma unroll
    for (int kh = 0; kh < 2; ++kh)
#pragma unroll
      for (int ni = 0; ni < 4; ++ni)
        bfr[kh][ni] = *(const bf16x8*)(bB + (wc * 64 + ni * 16 + lr) * 64 +
                                       (((kh * 4 + kg) ^ l7) * 8));
#pragma unroll
    for (int ph = 0; ph < 4; ++ph) {
      const int mh = ph >> 1, kh = ph & 1;
      bf16x8 af[4];
#pragma unroll
      for (int mi = 0; mi < 4; ++mi)
        af[mi] = *(const bf16x8*)(bA + (wr * 128 + mh * 64 + mi * 16 + lr) * 64 +
                                  (((kh * 4 + kg) ^ l7) * 8));
      __builtin_amdgcn_s_barrier();
      __builtin_amdgcn_s_setprio(1);
#pragma unroll
      for (int mi = 0; mi < 4; ++mi)
#pragma unroll
        for (int ni = 0; ni < 4; ++ni)
          acc[mh * 4 + mi][ni] = __builtin_amdgcn_mfma_f32_16x16x32_bf16(
              bfr[kh][ni], af[mi], acc[mh * 4 + mi][ni], 0, 0, 0);
      __builtin_amdgcn_s_setprio(0);
      __builtin_amdgcn_s_barrier();
    }
  }

  __syncthreads();
  if (bn >= 2048) {
#pragma unroll
    for (int mi = 0; mi < 8; ++mi)
#pragma unroll
      for (int ni = 0; ni < 4; ++ni) {
        int r = bm + wr * 128 + mi * 16 + lr;
        int c = bn + wc * 64 + ni * 16 + kg * 4 - 2048;
        int bh2 = (r >> 11) * 16 + (c >> 6);
        int j = r & 2047;
        u16* vrow = VT + ((size_t)bh2 * 64 + (c & 63)) * 2048 + j;
        f32x4 a = acc[mi][ni];
#pragma unroll
        for (int rr = 0; rr < 4; ++rr) vrow[(size_t)rr * 2048] = f2h(a[rr]);
      }
  } else {
    float scale = (bn < 1024) ? EKF : 1.0f;
#pragma unroll
    for (int mi = 0; mi < 8; ++mi)
#pragma unroll
      for (int ni = 0; ni < 4; ++ni) {
        int row = wr * 128 + mi * 16 + lr;
        u32 off = (u32)row * 256 + wc * 64 + (((ni * 4 + kg) ^ (lr & 6)) * 4);
        f32x4 a = acc[mi][ni];
        *(uint2*)((u16*)smem + off) =
            make_uint2(pack2(a[0] * scale, a[1] * scale), pack2(a[2] * scale, a[3] * scale));
      }
    __syncthreads();
#pragma unroll
    for (int i = 0; i < 16; ++i) {
      int row = i * 16 + (tid >> 5);
      int lc = tid & 31;
      int blk = lc >> 3, cc = lc & 7;
      uint4 v = *(const uint4*)((const u16*)smem + (u32)row * 256 + blk * 64 +
                                (((2 * cc) ^ (row & 6)) * 4));
      *(uint4*)(QK + (size_t)(bm + row) * 2048 + bn + blk * 64 + cc * 8) = v;
    }
  }
}

// ---------------- bf16 GEMM v10 (out-proj only) ----------------
template <int OUT_MODE, int BN>
__global__ __launch_bounds__(256) void gemm_bt_kernel(const u16* __restrict__ A,
                                                      const u16* __restrict__ BT,
                                                      void* __restrict__ Cv,
                                                      u16* __restrict__ VT,
                                                      int M, int N, int K) {
  const int NF = (BN == 128) ? 4 : 2;
  __shared__ __attribute__((aligned(16))) u16 sA[128 * 64];
  __shared__ __attribute__((aligned(16))) u16 sB[BN * 64];
  const int tid = threadIdx.x;
  const int wave = tid >> 6;
  const int lane = tid & 63;
  const int bm = blockIdx.y * 128;
  const int bn = blockIdx.x * BN;
  const int wm = (wave >> 1) * 64;
  const int wn = (wave & 1) * (BN / 2);
  const int lr = lane & 15;
  const int kg = lane >> 4;
  const int lr7 = lr & 7;

  const int sr = tid >> 3;
  const int sc = tid & 7;
  const int scg = (sc ^ (sr & 7)) * 8;
  const u16* pa = A + (size_t)(bm + sr) * K + scg;
  const u16* pb = BT + (size_t)(bn + sr) * K + scg;
  const u16* la = sA + wave * 512;
  const u16* lb = sB + wave * 512;

  f32x4 acc[4][NF];
#pragma unroll
  for (int i = 0; i < 4; i++)
#pragma unroll
    for (int j = 0; j < NF; j++) {
      f32x4 z = {0.f, 0.f, 0.f, 0.f};
      acc[i][j] = z;
    }

  for (int k0 = 0; k0 < K; k0 += 64) {
    __syncthreads();
#pragma unroll
    for (int i = 0; i < 4; ++i)
      gld_lds16(pa + (size_t)(i * 32) * K + k0, la + i * 2048);
#pragma unroll
    for (int i = 0; i < NF; ++i)
      gld_lds16(pb + (size_t)(i * 32) * K + k0, lb + i * 2048);
    __syncthreads();
#pragma unroll
    for (int kk = 0; kk < 2; ++kk) {
      bf16x8 af[4], bfr[NF];
      const int ch = ((kk * 4 + kg) ^ lr7) * 8;
#pragma unroll
      for (int mi = 0; mi < 4; mi++)
        af[mi] = *(const bf16x8*)(sA + (wm + mi * 16 + lr) * 64 + ch);
#pragma unroll
      for (int ni = 0; ni < NF; ni++)
        bfr[ni] = *(const bf16x8*)(sB + (wn + ni * 16 + lr) * 64 + ch);
#pragma unroll
      for (int mi = 0; mi < 4; mi++)
#pragma unroll
        for (int ni = 0; ni < NF; ni++)
          acc[mi][ni] = __builtin_amdgcn_mfma_f32_16x16x32_bf16(bfr[ni], af[mi], acc[mi][ni], 0, 0, 0);
    }
  }

  if (OUT_MODE == 0) {
    float* buf = (float*)sA;
    float* outp = (float*)Cv;
#pragma unroll
    for (int hc = 0; hc < 2; ++hc) {
      __syncthreads();
      if ((wave & 1) == hc) {
#pragma unroll
        for (int mi = 0; mi < 4; mi++)
#pragma unroll
          for (int ni = 0; ni < NF; ni++) {
            int row = wm + mi * 16 + lr;
            int cp = ((ni * 4 + kg) ^ lr7) * 4;
            *(f32x4*)(buf + row * 32 + cp) = acc[mi][ni];
          }
      }
      __syncthreads();
#pragma unroll
      for (int i = 0; i < 4; ++i) {
        int row = i * 32 + (tid >> 3);
        int lc = tid & 7;
        float4 v = *(const float4*)(buf + row * 32 + ((lc ^ (row & 7)) * 4));
        *(float4*)(outp + (size_t)(bm + row) * N + bn + hc * 32 + lc * 4) = v;
      }
    }
  } else if (bn >= 2048) {
#pragma unroll
    for (int mi = 0; mi < 4; mi++)
#pragma unroll
      for (int ni = 0; ni < NF; ni++) {
        int r = bm + wm + mi * 16 + lr;
        int cc = bn + wn + ni * 16 + kg * 4 - 2048;
        int bh2 = (r >> 11) * 16 + (cc >> 6);
        int j = r & 2047;
        u16* vrow = VT + ((size_t)bh2 * 64 + (cc & 63)) * 2048 + j;
        f32x4 a = acc[mi][ni];
#pragma unroll
        for (int rr = 0; rr < 4; rr++)
          vrow[(size_t)rr * 2048] = f2h(a[rr]);
      }
  } else {
    float scale = (bn < 1024) ? EKF : 1.0f;
    u16* buf = sA;
    u16* qkp = (u16*)Cv;
#pragma unroll
    for (int hc = 0; hc < 2; ++hc) {
      __syncthreads();
      if ((wave & 1) == hc) {
#pragma unroll
        for (int mi = 0; mi < 4; mi++)
#pragma unroll
          for (int ni = 0; ni < NF; ni++) {
            int row = wm + mi * 16 + lr;
            int sp = ((ni * 4 + kg) ^ (lr & 6)) * 4;
            f32x4 a = acc[mi][ni];
            *(uint2*)(buf + row * 64 + sp) =
                make_uint2(pack2(a[0] * scale, a[1] * scale),
                           pack2(a[2] * scale, a[3] * scale));
          }
      }
      __syncthreads();
#pragma unroll
      for (int i = 0; i < 4; ++i) {
        int row = i * 32 + (tid >> 3);
        int lc = tid & 7;
        uint4 v = *(const uint4*)(buf + row * 64 + (((2 * lc) ^ (row & 6)) * 4));
        *(uint4*)(qkp + (size_t)(bm + row) * 2048 + bn + hc * 64 + lc * 8) = v;
      }
    }
  }
}

// ---------------- MFMA flash attention v9: 16x16 base + causal j-split ----------------
// Work units (1536 blocks, heavy-first):
//   idx <  512 : A-half of qi>=16 tiles, j-tiles [0,16)        (16 rounds, no diag)
//   idx < 1024 : full tiles qi = 15 - ..., j-tiles [0, qi]     (1..16 rounds)
//   idx < 1536 : B-half of qi>=16 tiles (desc), j [16, qi]     (1..16 rounds, diag)
// No-max softmax => partial (O, lsum) combine additively. Split partners rendezvous
// via agent-scope counter: both store f32 partials (agent atomics, XCD-safe); the
// second to arrive combines partner + own regs, normalizes, writes bf16. No spinning.
__global__ __launch_bounds__(256, 4) void attn_mfma_kernel(const u16* __restrict__ qk,
                                                           const u16* __restrict__ vt,
                                                           u16* __restrict__ out,
                                                           float* __restrict__ OA,
                                                           float* __restrict__ OB,
                                                           float* __restrict__ LA,
                                                           float* __restrict__ LB,
                                                           u32* __restrict__ CNT) {
  __shared__ __attribute__((aligned(16))) u16 sK[2][64 * 64];  // [j][d] swizzled
  __shared__ __attribute__((aligned(16))) u16 sV[2][64 * 64];  // [d][j] swizzled
  __shared__ __attribute__((aligned(16))) u16 sP[4][16 * 64];  // [q][j] 8B-swizzled
  __shared__ int who;

  const int tid = threadIdx.x;
  const int wave = tid >> 6;
  const int lane = tid & 63;
  const int lr = lane & 15;  // q col (B), j/d row (A)
  const int kg = lane >> 4;  // k-group / row-quad
  const int l7 = lr & 7;

  int idx = blockIdx.x;
  int qi, bh, t0, t1, role;  // role 0=full, 1=A-half, 2=B-half
  if (idx < 512) {
    qi = 16 + (idx >> 5); bh = idx & 31; t0 = 0; t1 = 15; role = 1;
  } else if (idx < 1024) {
    int i2 = idx - 512;
    qi = 15 - (i2 >> 5); bh = i2 & 31; t0 = 0; t1 = qi; role = 0;
  } else {
    int i2 = idx - 1024;
    qi = 31 - (i2 >> 5); bh = i2 & 31; t0 = 16; t1 = qi; role = 2;
  }
  int b = bh >> 4, h = bh & 15;
  int q0 = qi * 64;

  const u16* qbase = qk + (size_t)b * 2048 * 2048 + h * 64;
  const u16* kbase = qbase + 1024;
  const u16* vbase = vt + (size_t)bh * 64 * 2048;
  u16* obase = out + (size_t)b * 2048 * 1024 + h * 64;

  const int sra = wave * 16 + (lane >> 3);
  const int srb = sra + 8;
  const int sc = lane & 7;
  const u32 koffA = (u32)sra * 2048 + (u32)((sc ^ (sra & 7)) * 8);
  const u32 koffB = (u32)srb * 2048 + (u32)((sc ^ (srb & 7)) * 8);
  const u32 ldsA = (wave * 2 + 0) * 512;
  const u32 ldsB = (wave * 2 + 1) * 512;

  const int qcol = q0 + wave * 16 + lr;
  bf16x8 qf0, qf1;
  {
    const u16* qrow = qbase + (size_t)qcol * 2048;
    qf0 = *(const bf16x8*)(qrow + kg * 8);
    qf1 = *(const bf16x8*)(qrow + 32 + kg * 8);
  }

  const u32 ka0 = (u32)(lr * 64 + ((kg ^ l7) * 8));
  const u32 ka1 = (u32)(lr * 64 + (((4 + kg) ^ l7) * 8));
  u16* const sPw = sP[wave];
  const u32 pr0 = (u32)(lr * 64 + (((kg * 2) ^ (l7 << 1)) * 4));
  const u32 pr1 = (u32)(lr * 64 + (((8 + kg * 2) ^ (l7 << 1)) * 4));

  f32x4 oacc[4];
#pragma unroll
  for (int i = 0; i < 4; ++i) {
    f32x4 z = {0.f, 0.f, 0.f, 0.f};
    oacc[i] = z;
  }
  float lsum = 0.f;

  {
    int j0 = t0 * 64;
    gld_lds16(kbase + (size_t)j0 * 2048 + koffA, sK[0] + ldsA);
    gld_lds16(kbase + (size_t)j0 * 2048 + koffB, sK[0] + ldsB);
    gld_lds16(vbase + j0 + koffA, sV[0] + ldsA);
    gld_lds16(vbase + j0 + koffB, sV[0] + ldsB);
  }
  __syncthreads();

  for (int t = t0; t <= t1; ++t) {
    if (t < t1) {
      int j1 = (t + 1) * 64;
      u16* dK = sK[(t + 1) & 1];
      u16* dV = sV[(t + 1) & 1];
      gld_lds16(kbase + (size_t)j1 * 2048 + koffA, dK + ldsA);
      gld_lds16(kbase + (size_t)j1 * 2048 + koffB, dK + ldsB);
      gld_lds16(vbase + j1 + koffA, dV + ldsA);
      gld_lds16(vbase + j1 + koffB, dV + ldsB);
    }
    const u16* sKb = sK[t & 1];
    const u16* sVb = sV[t & 1];
    const bool diag = (t == qi);

#pragma unroll
    for (int jt = 0; jt < 4; ++jt) {
      u16* pw = sPw + lr * 64 + (((jt * 4 + kg) ^ (l7 << 1)) * 4);
      if (!diag || jt <= wave) {
        bf16x8 kf0 = *(const bf16x8*)(sKb + jt * 1024 + ka0);
        bf16x8 kf1 = *(const bf16x8*)(sKb + jt * 1024 + ka1);
        f32x4 c = {0.f, 0.f, 0.f, 0.f};
        c = __builtin_amdgcn_mfma_f32_16x16x32_bf16(kf0, qf0, c, 0, 0, 0);
        c = __builtin_amdgcn_mfma_f32_16x16x32_bf16(kf1, qf1, c, 0, 0, 0);
        float p0 = exp2f(c[0]);
        float p1 = exp2f(c[1]);
        float p2 = exp2f(c[2]);
        float p3 = exp2f(c[3]);
        if (diag && jt == wave) {
          int jr = kg * 4;
          p0 = (jr + 0 <= lr) ? p0 : 0.f;
          p1 = (jr + 1 <= lr) ? p1 : 0.f;
          p2 = (jr + 2 <= lr) ? p2 : 0.f;
          p3 = (jr + 3 <= lr) ? p3 : 0.f;
        }
        lsum += (p0 + p1) + (p2 + p3);
        *(uint2*)pw = make_uint2(pkf16(p0, p1), pkf16(p2, p3));
      } else {
        *(uint2*)pw = make_uint2(0u, 0u);
      }
    }

    asm volatile("" ::: "memory");  // P writes precede P-frag reads (same wave)

    f16x8 pf0 = *(const f16x8*)(sPw + pr0);
    f16x8 pf1 = *(const f16x8*)(sPw + pr1);
#pragma unroll
    for (int dt = 0; dt < 4; ++dt) {
      f16x8 vf0 = *(const f16x8*)(sVb + dt * 1024 + ka0);
      f16x8 vf1 = *(const f16x8*)(sVb + dt * 1024 + ka1);
      oacc[dt] = __builtin_amdgcn_mfma_f32_16x16x32_f16(vf0, pf0, oacc[dt], 0, 0, 0);
      oacc[dt] = __builtin_amdgcn_mfma_f32_16x16x32_f16(vf1, pf1, oacc[dt], 0, 0, 0);
    }
    __syncthreads();
  }

  lsum += __shfl_xor(lsum, 16);
  lsum += __shfl_xor(lsum, 32);

  if (role == 0) {
    float inv = 1.0f / lsum;
    u16* orow = obase + (size_t)qcol * 1024;
#pragma unroll
    for (int dt = 0; dt < 4; ++dt) {
      uint2 o2 = make_uint2(pack2(oacc[dt][0] * inv, oacc[dt][1] * inv),
                            pack2(oacc[dt][2] * inv, oacc[dt][3] * inv));
      *(uint2*)(orow + dt * 16 + kg * 4) = o2;
    }
    return;
  }

  // ---- split rendezvous ----
  const int slot = (qi - 16) * 32 + bh;
  const int r = wave * 16 + lr;  // row within tile [0,64)
  float* Om = (role == 1 ? OA : OB) + (size_t)slot * 4096;
  float* Lm = (role == 1 ? LA : LB) + (size_t)slot * 64;
#pragma unroll
  for (int dt = 0; dt < 4; ++dt) {
    int d = dt * 16 + kg * 4;
#pragma unroll
    for (int j = 0; j < 4; ++j) stg_f32(Om + r * 64 + d + j, oacc[dt][j]);
  }
  if (kg == 0) stg_f32(Lm + r, lsum);
  __threadfence();
  __syncthreads();
  if (tid == 0)
    who = (int)__hip_atomic_fetch_add(CNT + slot, 1u, __ATOMIC_ACQ_REL,
                                      __HIP_MEMORY_SCOPE_AGENT);
  __syncthreads();
  if (who == 0) return;  // partner will combine
  __threadfence();

  const float* Op = (role == 1 ? OB : OA) + (size_t)slot * 4096;
  const float* Lp = (role == 1 ? LB : LA) + (size_t)slot * 64;
  float inv = 1.0f / (lsum + ldg_f32(Lp + r));
  u16* orow = obase + (size_t)qcol * 1024;
#pragma unroll
  for (int dt = 0; dt < 4; ++dt) {
    int d = dt * 16 + kg * 4;
    float o0 = oacc[dt][0] + ldg_f32(Op + r * 64 + d + 0);
    float o1 = oacc[dt][1] + ldg_f32(Op + r * 64 + d + 1);
    float o2 = oacc[dt][2] + ldg_f32(Op + r * 64 + d + 2);
    float o3 = oacc[dt][3] + ldg_f32(Op + r * 64 + d + 3);
    uint2 o2v = make_uint2(pack2(o0 * inv, o1 * inv), pack2(o2 * inv, o3 * inv));
    *(uint2*)(orow + dt * 16 + kg * 4) = o2v;
  }
}

// ---------------- launch ----------------
extern "C" void kernel_launch(void* const* d_in, const int* in_sizes, int n_in,
                              void* d_out, int out_size, void* d_ws, size_t ws_size,
                              hipStream_t stream) {
  const float* x = (const float*)d_in[0];      // [2,2048,1024]
  const float* w_qkv = (const float*)d_in[1];  // [1024,3072]
  const float* w_out = (const float*)d_in[2];  // [1024,1024]
  float* out = (float*)d_out;                  // [2,2048,1024] fp32

  char* ws = (char*)d_ws;
  u16* xb    = (u16*)(ws);                //  8 MB: x bf16 [4096,1024]
  u16* wqkvT = (u16*)(ws + (8u << 20));   //  6 MB: w_qkv^T bf16 [3072,1024]
  u16* woutT = (u16*)(ws + (14u << 20));  //  2 MB: w_out^T bf16 [1024,1024]
  u16* qkb   = (u16*)(ws + (16u << 20));  // 16 MB: q|k bf16 [4096,2048]
  u16* vtb   = (u16*)(ws + (32u << 20));  //  8 MB: V^T f16 [32,64,2048]
  u16* attn  = (u16*)(ws + (40u << 20));  //  8 MB: attn out bf16 [4096,1024]
  // split-attention rendezvous buffers
  float* OA  = (float*)(ws + (48u << 20));               // 8 MB: 512 x 64x64 f32
  float* OB  = (float*)(ws + (56u << 20));               // 8 MB
  float* LA  = (float*)(ws + (64u << 20));               // 128 KB: 512 x 64 f32
  float* LB  = (float*)(ws + (64u << 20) + (128u << 10));
  u32*  CNT  = (u32*)(ws + (64u << 20) + (256u << 10));  // 2 KB: 512 counters

  prepass_kernel<<<5121, 256, 0, stream>>>(x, w_qkv, w_out, xb, wqkvT, woutT, CNT);

  gemm_qkv256_kernel<<<192, 512, 0, stream>>>(xb, wqkvT, qkb, vtb);

  attn_mfma_kernel<<<1536, 256, 0, stream>>>(qkb, vtb, attn, OA, OB, LA, LB, CNT);

  gemm_bt_kernel<0, 64><<<dim3(1024 / 64, 4096 / 128), 256, 0, stream>>>(
      attn, woutT, (void*)out, nullptr, 4096, 1024, 1024);
}

// Round 4
// 174.146 us; speedup vs baseline: 2.2148x; 2.2148x over previous
//
#include <hip/hip_runtime.h>

typedef unsigned short u16;
typedef unsigned int u32;

typedef __bf16 bf16x8 __attribute__((ext_vector_type(8)));
typedef _Float16 f16x8 __attribute__((ext_vector_type(8)));
typedef float f32x4 __attribute__((ext_vector_type(4)));

typedef __attribute__((address_space(1))) u32 as1_u32;
typedef __attribute__((address_space(3))) u32 as3_u32;

#define EKF 0.18033688011112042f  // 0.125 * log2(e), folded into Q at GEMM1

__device__ __forceinline__ u16 f2bf(float x) {
  u32 u = __float_as_uint(x);
  u = u + 0x7fffu + ((u >> 16) & 1u);   // RNE
  return (u16)(u >> 16);
}
__device__ __forceinline__ u32 pack2(float a, float b) {
  return (u32)f2bf(a) | ((u32)f2bf(b) << 16);
}
__device__ __forceinline__ u32 pkf16(float a, float b) {
  return __builtin_bit_cast(u32, __builtin_amdgcn_cvt_pkrtz(a, b));
}
__device__ __forceinline__ u16 f2h(float a) {
  return (u16)(pkf16(a, a) & 0xffffu);
}
__device__ __forceinline__ void gld_lds16(const u16* g, const u16* l) {
  __builtin_amdgcn_global_load_lds((const as1_u32*)g, (as3_u32*)l, 16, 0, 0);
}

// ---------------- fused prepass: x cast + both weight transposes ----------------
__global__ __launch_bounds__(256) void prepass_kernel(const float* __restrict__ x,
                                                      const float* __restrict__ w_qkv,
                                                      const float* __restrict__ w_out,
                                                      u16* __restrict__ xb,
                                                      u16* __restrict__ wqkvT,
                                                      u16* __restrict__ woutT) {
  __shared__ float tile[64][65];
  int bid = blockIdx.x;
  int t = threadIdx.x;
  if (bid < 4096) {
    int i = bid * 256 + t;
    float4 v = ((const float4*)x)[i];
    uint2 r;
    r.x = pack2(v.x, v.y);
    r.y = pack2(v.z, v.w);
    ((uint2*)xb)[i] = r;
    return;
  }
  const float* W;
  u16* WT;
  int K, N, bx, by;
  if (bid < 4096 + 768) {
    int b2 = bid - 4096;
    W = w_qkv; WT = wqkvT; K = 1024; N = 3072; bx = b2 & 15; by = b2 >> 4;
  } else {
    int b2 = bid - 4864;
    W = w_out; WT = woutT; K = 1024; N = 1024; bx = b2 & 15; by = b2 >> 4;
  }
  int k0 = bx * 64, n0 = by * 64;
  int r = t >> 4, c4 = (t & 15) * 4;
#pragma unroll
  for (int i = 0; i < 4; ++i) {
    int row = r + i * 16;
    float4 v = *(const float4*)&W[(size_t)(k0 + row) * N + n0 + c4];
    tile[row][c4 + 0] = v.x; tile[row][c4 + 1] = v.y;
    tile[row][c4 + 2] = v.z; tile[row][c4 + 3] = v.w;
  }
  __syncthreads();
#pragma unroll
  for (int i = 0; i < 4; ++i) {
    int n = r + i * 16;
    uint2 o;
    o.x = pack2(tile[c4 + 0][n], tile[c4 + 1][n]);
    o.y = pack2(tile[c4 + 2][n], tile[c4 + 3][n]);
    *(uint2*)&WT[(size_t)(n0 + n) * K + k0 + c4] = o;
  }
}

// ---------------- 256x256 8-phase QKV GEMM (unchanged from R1) ----------------
__global__ __launch_bounds__(512, 2) void gemm_qkv256_kernel(const u16* __restrict__ A,
                                                             const u16* __restrict__ BT,
                                                             u16* __restrict__ QK,
                                                             u16* __restrict__ VT) {
  __shared__ __attribute__((aligned(16))) u16 smem[65536];  // 128 KiB -> 1 block/CU
  const int tid = threadIdx.x;
  const int wave = tid >> 6;
  const int lane = tid & 63;
  const int lr = lane & 15;
  const int kg = lane >> 4;
  const int l7 = lr & 7;
  const int wr = wave >> 2;   // 0..1 : M half
  const int wc = wave & 3;    // 0..3 : N quarter

  int b = blockIdx.x;
  int sw = (b & 7) * 24 + (b >> 3);
  const int bn = (sw % 12) * 256;
  const int bm = (sw / 12) * 256;

  const int srow = tid >> 3;
  const int scg = ((tid & 7) ^ (srow & 7)) * 8;  // swizzled source col (u16)
  const u16* pa = A + (size_t)(bm + srow) * 1024 + scg;
  const u16* pb = BT + (size_t)(bn + srow) * 1024 + scg;
  const u32 lw = (u32)wave * 512;

  f32x4 acc[8][4];
#pragma unroll
  for (int i = 0; i < 8; ++i)
#pragma unroll
    for (int j = 0; j < 4; ++j) {
      f32x4 z = {0.f, 0.f, 0.f, 0.f};
      acc[i][j] = z;
    }

  {
    u16* dA = (u16*)smem;
    u16* dB = (u16*)smem + 16384;
#pragma unroll
    for (int i = 0; i < 4; ++i) gld_lds16(pa + (size_t)(i * 64) * 1024, dA + lw + i * 4096);
#pragma unroll
    for (int i = 0; i < 4; ++i) gld_lds16(pb + (size_t)(i * 64) * 1024, dB + lw + i * 4096);
  }

  for (int t = 0; t < 16; ++t) {
    __syncthreads();
    const u16* bA = smem + (t & 1) * 32768;
    const u16* bB = bA + 16384;
    if (t + 1 < 16) {
      u16* dA = (u16*)smem + ((t + 1) & 1) * 32768;
      u16* dB = dA + 16384;
      const int k1 = (t + 1) * 64;
#pragma unroll
      for (int i = 0; i < 4; ++i) gld_lds16(pa + (size_t)(i * 64) * 1024 + k1, dA + lw + i * 4096);
#pragma unroll
      for (int i = 0; i < 4; ++i) gld_lds16(pb + (size_t)(i * 64) * 1024 + k1, dB + lw + i * 4096);
    }
    bf16x8 bfr[2][4];
#pragma unroll
    for (int kh = 0; kh < 2; ++kh)
#pragma unroll
      for (int ni = 0; ni < 4; ++ni)
        bfr[kh][ni] = *(const bf16x8*)(bB + (wc * 64 + ni * 16 + lr) * 64 +
                                       (((kh * 4 + kg) ^ l7) * 8));
#pragma unroll
    for (int ph = 0; ph < 4; ++ph) {
      const int mh = ph >> 1, kh = ph & 1;
      bf16x8 af[4];
#pragma unroll
      for (int mi = 0; mi < 4; ++mi)
        af[mi] = *(const bf16x8*)(bA + (wr * 128 + mh * 64 + mi * 16 + lr) * 64 +
                                  (((kh * 4 + kg) ^ l7) * 8));
      __builtin_amdgcn_s_barrier();
      __builtin_amdgcn_s_setprio(1);
#pragma unroll
      for (int mi = 0; mi < 4; ++mi)
#pragma unroll
        for (int ni = 0; ni < 4; ++ni)
          acc[mh * 4 + mi][ni] = __builtin_amdgcn_mfma_f32_16x16x32_bf16(
              bfr[kh][ni], af[mi], acc[mh * 4 + mi][ni], 0, 0, 0);
      __builtin_amdgcn_s_setprio(0);
      __builtin_amdgcn_s_barrier();
    }
  }

  __syncthreads();
  if (bn >= 2048) {
#pragma unroll
    for (int mi = 0; mi < 8; ++mi)
#pragma unroll
      for (int ni = 0; ni < 4; ++ni) {
        int r = bm + wr * 128 + mi * 16 + lr;
        int c = bn + wc * 64 + ni * 16 + kg * 4 - 2048;
        int bh2 = (r >> 11) * 16 + (c >> 6);
        int j = r & 2047;
        u16* vrow = VT + ((size_t)bh2 * 64 + (c & 63)) * 2048 + j;
        f32x4 a = acc[mi][ni];
#pragma unroll
        for (int rr = 0; rr < 4; ++rr) vrow[(size_t)rr * 2048] = f2h(a[rr]);
      }
  } else {
    float scale = (bn < 1024) ? EKF : 1.0f;
#pragma unroll
    for (int mi = 0; mi < 8; ++mi)
#pragma unroll
      for (int ni = 0; ni < 4; ++ni) {
        int row = wr * 128 + mi * 16 + lr;
        u32 off = (u32)row * 256 + wc * 64 + (((ni * 4 + kg) ^ (lr & 6)) * 4);
        f32x4 a = acc[mi][ni];
        *(uint2*)((u16*)smem + off) =
            make_uint2(pack2(a[0] * scale, a[1] * scale), pack2(a[2] * scale, a[3] * scale));
      }
    __syncthreads();
#pragma unroll
    for (int i = 0; i < 16; ++i) {
      int row = i * 16 + (tid >> 5);
      int lc = tid & 31;
      int blk = lc >> 3, cc = lc & 7;
      uint4 v = *(const uint4*)((const u16*)smem + (u32)row * 256 + blk * 64 +
                                (((2 * cc) ^ (row & 6)) * 4));
      *(uint4*)(QK + (size_t)(bm + row) * 2048 + bn + blk * 64 + cc * 8) = v;
    }
  }
}

// ---------------- bf16 GEMM v10 (out-proj only) ----------------
template <int OUT_MODE, int BN>
__global__ __launch_bounds__(256) void gemm_bt_kernel(const u16* __restrict__ A,
                                                      const u16* __restrict__ BT,
                                                      void* __restrict__ Cv,
                                                      u16* __restrict__ VT,
                                                      int M, int N, int K) {
  const int NF = (BN == 128) ? 4 : 2;
  __shared__ __attribute__((aligned(16))) u16 sA[128 * 64];
  __shared__ __attribute__((aligned(16))) u16 sB[BN * 64];
  const int tid = threadIdx.x;
  const int wave = tid >> 6;
  const int lane = tid & 63;
  const int bm = blockIdx.y * 128;
  const int bn = blockIdx.x * BN;
  const int wm = (wave >> 1) * 64;
  const int wn = (wave & 1) * (BN / 2);
  const int lr = lane & 15;
  const int kg = lane >> 4;
  const int lr7 = lr & 7;

  const int sr = tid >> 3;
  const int sc = tid & 7;
  const int scg = (sc ^ (sr & 7)) * 8;
  const u16* pa = A + (size_t)(bm + sr) * K + scg;
  const u16* pb = BT + (size_t)(bn + sr) * K + scg;
  const u16* la = sA + wave * 512;
  const u16* lb = sB + wave * 512;

  f32x4 acc[4][NF];
#pragma unroll
  for (int i = 0; i < 4; i++)
#pragma unroll
    for (int j = 0; j < NF; j++) {
      f32x4 z = {0.f, 0.f, 0.f, 0.f};
      acc[i][j] = z;
    }

  for (int k0 = 0; k0 < K; k0 += 64) {
    __syncthreads();
#pragma unroll
    for (int i = 0; i < 4; ++i)
      gld_lds16(pa + (size_t)(i * 32) * K + k0, la + i * 2048);
#pragma unroll
    for (int i = 0; i < NF; ++i)
      gld_lds16(pb + (size_t)(i * 32) * K + k0, lb + i * 2048);
    __syncthreads();
#pragma unroll
    for (int kk = 0; kk < 2; ++kk) {
      bf16x8 af[4], bfr[NF];
      const int ch = ((kk * 4 + kg) ^ lr7) * 8;
#pragma unroll
      for (int mi = 0; mi < 4; mi++)
        af[mi] = *(const bf16x8*)(sA + (wm + mi * 16 + lr) * 64 + ch);
#pragma unroll
      for (int ni = 0; ni < NF; ni++)
        bfr[ni] = *(const bf16x8*)(sB + (wn + ni * 16 + lr) * 64 + ch);
#pragma unroll
      for (int mi = 0; mi < 4; mi++)
#pragma unroll
        for (int ni = 0; ni < NF; ni++)
          acc[mi][ni] = __builtin_amdgcn_mfma_f32_16x16x32_bf16(bfr[ni], af[mi], acc[mi][ni], 0, 0, 0);
    }
  }

  if (OUT_MODE == 0) {
    float* buf = (float*)sA;
    float* outp = (float*)Cv;
#pragma unroll
    for (int hc = 0; hc < 2; ++hc) {
      __syncthreads();
      if ((wave & 1) == hc) {
#pragma unroll
        for (int mi = 0; mi < 4; mi++)
#pragma unroll
          for (int ni = 0; ni < NF; ni++) {
            int row = wm + mi * 16 + lr;
            int cp = ((ni * 4 + kg) ^ lr7) * 4;
            *(f32x4*)(buf + row * 32 + cp) = acc[mi][ni];
          }
      }
      __syncthreads();
#pragma unroll
      for (int i = 0; i < 4; ++i) {
        int row = i * 32 + (tid >> 3);
        int lc = tid & 7;
        float4 v = *(const float4*)(buf + row * 32 + ((lc ^ (row & 7)) * 4));
        *(float4*)(outp + (size_t)(bm + row) * N + bn + hc * 32 + lc * 4) = v;
      }
    }
  } else if (bn >= 2048) {
#pragma unroll
    for (int mi = 0; mi < 4; mi++)
#pragma unroll
      for (int ni = 0; ni < NF; ni++) {
        int r = bm + wm + mi * 16 + lr;
        int cc = bn + wn + ni * 16 + kg * 4 - 2048;
        int bh2 = (r >> 11) * 16 + (cc >> 6);
        int j = r & 2047;
        u16* vrow = VT + ((size_t)bh2 * 64 + (cc & 63)) * 2048 + j;
        f32x4 a = acc[mi][ni];
#pragma unroll
        for (int rr = 0; rr < 4; rr++)
          vrow[(size_t)rr * 2048] = f2h(a[rr]);
      }
  } else {
    float scale = (bn < 1024) ? EKF : 1.0f;
    u16* buf = sA;
    u16* qkp = (u16*)Cv;
#pragma unroll
    for (int hc = 0; hc < 2; ++hc) {
      __syncthreads();
      if ((wave & 1) == hc) {
#pragma unroll
        for (int mi = 0; mi < 4; mi++)
#pragma unroll
          for (int ni = 0; ni < NF; ni++) {
            int row = wm + mi * 16 + lr;
            int sp = ((ni * 4 + kg) ^ (lr & 6)) * 4;
            f32x4 a = acc[mi][ni];
            *(uint2*)(buf + row * 64 + sp) =
                make_uint2(pack2(a[0] * scale, a[1] * scale),
                           pack2(a[2] * scale, a[3] * scale));
          }
      }
      __syncthreads();
#pragma unroll
      for (int i = 0; i < 4; ++i) {
        int row = i * 32 + (tid >> 3);
        int lc = tid & 7;
        uint4 v = *(const uint4*)(buf + row * 64 + (((2 * lc) ^ (row & 6)) * 4));
        *(uint4*)(qkp + (size_t)(bm + row) * 2048 + bn + hc * 64 + lc * 8) = v;
      }
    }
  }
}

// ---------------- MFMA flash attention v10: R1 body + complementary tile pairing ----
// 512 blocks: block (pi, bh), pi in [0,16). Processes tile qi=pi (pi+1 rounds) then
// tile qi=31-pi (32-pi rounds) -> every block does exactly 33 rounds. Perfect
// makespan balance with zero extra memory traffic, no rendezvous. Inner loop is
// the verified R1 body, unchanged.
__global__ __launch_bounds__(256, 4) void attn_mfma_kernel(const u16* __restrict__ qk,
                                                           const u16* __restrict__ vt,
                                                           u16* __restrict__ out) {
  __shared__ __attribute__((aligned(16))) u16 sK[2][64 * 64];  // [j][d] swizzled
  __shared__ __attribute__((aligned(16))) u16 sV[2][64 * 64];  // [d][j] swizzled
  __shared__ __attribute__((aligned(16))) u16 sP[4][16 * 64];  // [q][j] 8B-swizzled

  const int tid = threadIdx.x;
  const int wave = tid >> 6;
  const int lane = tid & 63;
  const int lr = lane & 15;  // q col (B), j/d row (A)
  const int kg = lane >> 4;  // k-group / row-quad
  const int l7 = lr & 7;

  const int idx = blockIdx.x;
  const int bh = idx & 31;
  const int pi = idx >> 5;  // 0..15
  const int b = bh >> 4, h = bh & 15;

  const u16* qbase = qk + (size_t)b * 2048 * 2048 + h * 64;
  const u16* kbase = qbase + 1024;
  const u16* vbase = vt + (size_t)bh * 64 * 2048;
  u16* obase = out + (size_t)b * 2048 * 1024 + h * 64;

  const int sra = wave * 16 + (lane >> 3);
  const int srb = sra + 8;
  const int sc = lane & 7;
  const u32 koffA = (u32)sra * 2048 + (u32)((sc ^ (sra & 7)) * 8);
  const u32 koffB = (u32)srb * 2048 + (u32)((sc ^ (srb & 7)) * 8);
  const u32 ldsA = (wave * 2 + 0) * 512;
  const u32 ldsB = (wave * 2 + 1) * 512;

  const u32 ka0 = (u32)(lr * 64 + ((kg ^ l7) * 8));
  const u32 ka1 = (u32)(lr * 64 + (((4 + kg) ^ l7) * 8));
  u16* const sPw = sP[wave];
  const u32 pr0 = (u32)(lr * 64 + (((kg * 2) ^ (l7 << 1)) * 4));
  const u32 pr1 = (u32)(lr * 64 + (((8 + kg * 2) ^ (l7 << 1)) * 4));

  for (int half = 0; half < 2; ++half) {
    const int qi = half ? (31 - pi) : pi;
    const int q0 = qi * 64;
    const int qcol = q0 + wave * 16 + lr;

    bf16x8 qf0, qf1;
    {
      const u16* qrow = qbase + (size_t)qcol * 2048;
      qf0 = *(const bf16x8*)(qrow + kg * 8);
      qf1 = *(const bf16x8*)(qrow + 32 + kg * 8);
    }

    f32x4 oacc[4];
#pragma unroll
    for (int i = 0; i < 4; ++i) {
      f32x4 z = {0.f, 0.f, 0.f, 0.f};
      oacc[i] = z;
    }
    float lsum = 0.f;

    const int nrounds = qi + 1;
    gld_lds16(kbase + koffA, sK[0] + ldsA);
    gld_lds16(kbase + koffB, sK[0] + ldsB);
    gld_lds16(vbase + koffA, sV[0] + ldsA);
    gld_lds16(vbase + koffB, sV[0] + ldsB);
    __syncthreads();

    for (int t = 0; t < nrounds; ++t) {
      if (t + 1 < nrounds) {
        int j1 = (t + 1) * 64;
        u16* dK = sK[(t + 1) & 1];
        u16* dV = sV[(t + 1) & 1];
        gld_lds16(kbase + (size_t)j1 * 2048 + koffA, dK + ldsA);
        gld_lds16(kbase + (size_t)j1 * 2048 + koffB, dK + ldsB);
        gld_lds16(vbase + j1 + koffA, dV + ldsA);
        gld_lds16(vbase + j1 + koffB, dV + ldsB);
      }
      const u16* sKb = sK[t & 1];
      const u16* sVb = sV[t & 1];
      const bool diag = (t == qi);

#pragma unroll
      for (int jt = 0; jt < 4; ++jt) {
        u16* pw = sPw + lr * 64 + (((jt * 4 + kg) ^ (l7 << 1)) * 4);
        if (!diag || jt <= wave) {
          bf16x8 kf0 = *(const bf16x8*)(sKb + jt * 1024 + ka0);
          bf16x8 kf1 = *(const bf16x8*)(sKb + jt * 1024 + ka1);
          f32x4 c = {0.f, 0.f, 0.f, 0.f};
          c = __builtin_amdgcn_mfma_f32_16x16x32_bf16(kf0, qf0, c, 0, 0, 0);
          c = __builtin_amdgcn_mfma_f32_16x16x32_bf16(kf1, qf1, c, 0, 0, 0);
          float p0 = exp2f(c[0]);
          float p1 = exp2f(c[1]);
          float p2 = exp2f(c[2]);
          float p3 = exp2f(c[3]);
          if (diag && jt == wave) {
            int jr = kg * 4;
            p0 = (jr + 0 <= lr) ? p0 : 0.f;
            p1 = (jr + 1 <= lr) ? p1 : 0.f;
            p2 = (jr + 2 <= lr) ? p2 : 0.f;
            p3 = (jr + 3 <= lr) ? p3 : 0.f;
          }
          lsum += (p0 + p1) + (p2 + p3);
          *(uint2*)pw = make_uint2(pkf16(p0, p1), pkf16(p2, p3));
        } else {
          *(uint2*)pw = make_uint2(0u, 0u);
        }
      }

      asm volatile("" ::: "memory");  // P writes precede P-frag reads (same wave)

      f16x8 pf0 = *(const f16x8*)(sPw + pr0);
      f16x8 pf1 = *(const f16x8*)(sPw + pr1);
#pragma unroll
      for (int dt = 0; dt < 4; ++dt) {
        f16x8 vf0 = *(const f16x8*)(sVb + dt * 1024 + ka0);
        f16x8 vf1 = *(const f16x8*)(sVb + dt * 1024 + ka1);
        oacc[dt] = __builtin_amdgcn_mfma_f32_16x16x32_f16(vf0, pf0, oacc[dt], 0, 0, 0);
        oacc[dt] = __builtin_amdgcn_mfma_f32_16x16x32_f16(vf1, pf1, oacc[dt], 0, 0, 0);
      }
      __syncthreads();
    }

    lsum += __shfl_xor(lsum, 16);
    lsum += __shfl_xor(lsum, 32);
    float inv = 1.0f / lsum;

    u16* orow = obase + (size_t)qcol * 1024;
#pragma unroll
    for (int dt = 0; dt < 4; ++dt) {
      uint2 o2 = make_uint2(pack2(oacc[dt][0] * inv, oacc[dt][1] * inv),
                            pack2(oacc[dt][2] * inv, oacc[dt][3] * inv));
      *(uint2*)(orow + dt * 16 + kg * 4) = o2;
    }
  }
}

// ---------------- launch ----------------
extern "C" void kernel_launch(void* const* d_in, const int* in_sizes, int n_in,
                              void* d_out, int out_size, void* d_ws, size_t ws_size,
                              hipStream_t stream) {
  const float* x = (const float*)d_in[0];      // [2,2048,1024]
  const float* w_qkv = (const float*)d_in[1];  // [1024,3072]
  const float* w_out = (const float*)d_in[2];  // [1024,1024]
  float* out = (float*)d_out;                  // [2,2048,1024] fp32

  char* ws = (char*)d_ws;
  u16* xb    = (u16*)(ws);                //  8 MB: x bf16 [4096,1024]
  u16* wqkvT = (u16*)(ws + (8u << 20));   //  6 MB: w_qkv^T bf16 [3072,1024]
  u16* woutT = (u16*)(ws + (14u << 20));  //  2 MB: w_out^T bf16 [1024,1024]
  u16* qkb   = (u16*)(ws + (16u << 20));  // 16 MB: q|k bf16 [4096,2048]
  u16* vtb   = (u16*)(ws + (32u << 20));  //  8 MB: V^T f16 [32,64,2048]
  u16* attn  = (u16*)(ws + (40u << 20));  //  8 MB: attn out bf16 [4096,1024]

  prepass_kernel<<<5120, 256, 0, stream>>>(x, w_qkv, w_out, xb, wqkvT, woutT);

  gemm_qkv256_kernel<<<192, 512, 0, stream>>>(xb, wqkvT, qkb, vtb);

  attn_mfma_kernel<<<512, 256, 0, stream>>>(qkb, vtb, attn);

  gemm_bt_kernel<0, 64><<<dim3(1024 / 64, 4096 / 128), 256, 0, stream>>>(
      attn, woutT, (void*)out, nullptr, 4096, 1024, 1024);
}

// Round 5
// 163.746 us; speedup vs baseline: 2.3555x; 1.0635x over previous
//
#include <hip/hip_runtime.h>

typedef unsigned short u16;
typedef unsigned int u32;

typedef __bf16 bf16x8 __attribute__((ext_vector_type(8)));
typedef _Float16 f16x8 __attribute__((ext_vector_type(8)));
typedef float f32x4 __attribute__((ext_vector_type(4)));

typedef __attribute__((address_space(1))) u32 as1_u32;
typedef __attribute__((address_space(3))) u32 as3_u32;

#define EKF 0.18033688011112042f  // 0.125 * log2(e), folded into Q at GEMM1

__device__ __forceinline__ u16 f2bf(float x) {
  u32 u = __float_as_uint(x);
  u = u + 0x7fffu + ((u >> 16) & 1u);   // RNE
  return (u16)(u >> 16);
}
__device__ __forceinline__ u32 pack2(float a, float b) {
  return (u32)f2bf(a) | ((u32)f2bf(b) << 16);
}
__device__ __forceinline__ u32 pkf16(float a, float b) {
  return __builtin_bit_cast(u32, __builtin_amdgcn_cvt_pkrtz(a, b));
}
__device__ __forceinline__ u16 f2h(float a) {
  return (u16)(pkf16(a, a) & 0xffffu);
}
__device__ __forceinline__ void gld_lds16(const u16* g, const u16* l) {
  __builtin_amdgcn_global_load_lds((const as1_u32*)g, (as3_u32*)l, 16, 0, 0);
}

// ---------------- fused prepass: x cast + both weight transposes ----------------
__global__ __launch_bounds__(256) void prepass_kernel(const float* __restrict__ x,
                                                      const float* __restrict__ w_qkv,
                                                      const float* __restrict__ w_out,
                                                      u16* __restrict__ xb,
                                                      u16* __restrict__ wqkvT,
                                                      u16* __restrict__ woutT) {
  __shared__ float tile[64][65];
  int bid = blockIdx.x;
  int t = threadIdx.x;
  if (bid < 4096) {
    int i = bid * 256 + t;
    float4 v = ((const float4*)x)[i];
    uint2 r;
    r.x = pack2(v.x, v.y);
    r.y = pack2(v.z, v.w);
    ((uint2*)xb)[i] = r;
    return;
  }
  const float* W;
  u16* WT;
  int K, N, bx, by;
  if (bid < 4096 + 768) {
    int b2 = bid - 4096;
    W = w_qkv; WT = wqkvT; K = 1024; N = 3072; bx = b2 & 15; by = b2 >> 4;
  } else {
    int b2 = bid - 4864;
    W = w_out; WT = woutT; K = 1024; N = 1024; bx = b2 & 15; by = b2 >> 4;
  }
  int k0 = bx * 64, n0 = by * 64;
  int r = t >> 4, c4 = (t & 15) * 4;
#pragma unroll
  for (int i = 0; i < 4; ++i) {
    int row = r + i * 16;
    float4 v = *(const float4*)&W[(size_t)(k0 + row) * N + n0 + c4];
    tile[row][c4 + 0] = v.x; tile[row][c4 + 1] = v.y;
    tile[row][c4 + 2] = v.z; tile[row][c4 + 3] = v.w;
  }
  __syncthreads();
#pragma unroll
  for (int i = 0; i < 4; ++i) {
    int n = r + i * 16;
    uint2 o;
    o.x = pack2(tile[c4 + 0][n], tile[c4 + 1][n]);
    o.y = pack2(tile[c4 + 2][n], tile[c4 + 3][n]);
    *(uint2*)&WT[(size_t)(n0 + n) * K + k0 + c4] = o;
  }
}

// ---------------- 256x256 8-phase QKV GEMM (unchanged from R1) ----------------
__global__ __launch_bounds__(512, 2) void gemm_qkv256_kernel(const u16* __restrict__ A,
                                                             const u16* __restrict__ BT,
                                                             u16* __restrict__ QK,
                                                             u16* __restrict__ VT) {
  __shared__ __attribute__((aligned(16))) u16 smem[65536];  // 128 KiB -> 1 block/CU
  const int tid = threadIdx.x;
  const int wave = tid >> 6;
  const int lane = tid & 63;
  const int lr = lane & 15;
  const int kg = lane >> 4;
  const int l7 = lr & 7;
  const int wr = wave >> 2;   // 0..1 : M half
  const int wc = wave & 3;    // 0..3 : N quarter

  int b = blockIdx.x;
  int sw = (b & 7) * 24 + (b >> 3);
  const int bn = (sw % 12) * 256;
  const int bm = (sw / 12) * 256;

  const int srow = tid >> 3;
  const int scg = ((tid & 7) ^ (srow & 7)) * 8;  // swizzled source col (u16)
  const u16* pa = A + (size_t)(bm + srow) * 1024 + scg;
  const u16* pb = BT + (size_t)(bn + srow) * 1024 + scg;
  const u32 lw = (u32)wave * 512;

  f32x4 acc[8][4];
#pragma unroll
  for (int i = 0; i < 8; ++i)
#pragma unroll
    for (int j = 0; j < 4; ++j) {
      f32x4 z = {0.f, 0.f, 0.f, 0.f};
      acc[i][j] = z;
    }

  {
    u16* dA = (u16*)smem;
    u16* dB = (u16*)smem + 16384;
#pragma unroll
    for (int i = 0; i < 4; ++i) gld_lds16(pa + (size_t)(i * 64) * 1024, dA + lw + i * 4096);
#pragma unroll
    for (int i = 0; i < 4; ++i) gld_lds16(pb + (size_t)(i * 64) * 1024, dB + lw + i * 4096);
  }

  for (int t = 0; t < 16; ++t) {
    __syncthreads();
    const u16* bA = smem + (t & 1) * 32768;
    const u16* bB = bA + 16384;
    if (t + 1 < 16) {
      u16* dA = (u16*)smem + ((t + 1) & 1) * 32768;
      u16* dB = dA + 16384;
      const int k1 = (t + 1) * 64;
#pragma unroll
      for (int i = 0; i < 4; ++i) gld_lds16(pa + (size_t)(i * 64) * 1024 + k1, dA + lw + i * 4096);
#pragma unroll
      for (int i = 0; i < 4; ++i) gld_lds16(pb + (size_t)(i * 64) * 1024 + k1, dB + lw + i * 4096);
    }
    bf16x8 bfr[2][4];
#pragma unroll
    for (int kh = 0; kh < 2; ++kh)
#pragma unroll
      for (int ni = 0; ni < 4; ++ni)
        bfr[kh][ni] = *(const bf16x8*)(bB + (wc * 64 + ni * 16 + lr) * 64 +
                                       (((kh * 4 + kg) ^ l7) * 8));
#pragma unroll
    for (int ph = 0; ph < 4; ++ph) {
      const int mh = ph >> 1, kh = ph & 1;
      bf16x8 af[4];
#pragma unroll
      for (int mi = 0; mi < 4; ++mi)
        af[mi] = *(const bf16x8*)(bA + (wr * 128 + mh * 64 + mi * 16 + lr) * 64 +
                                  (((kh * 4 + kg) ^ l7) * 8));
      __builtin_amdgcn_s_barrier();
      __builtin_amdgcn_s_setprio(1);
#pragma unroll
      for (int mi = 0; mi < 4; ++mi)
#pragma unroll
        for (int ni = 0; ni < 4; ++ni)
          acc[mh * 4 + mi][ni] = __builtin_amdgcn_mfma_f32_16x16x32_bf16(
              bfr[kh][ni], af[mi], acc[mh * 4 + mi][ni], 0, 0, 0);
      __builtin_amdgcn_s_setprio(0);
      __builtin_amdgcn_s_barrier();
    }
  }

  __syncthreads();
  if (bn >= 2048) {
#pragma unroll
    for (int mi = 0; mi < 8; ++mi)
#pragma unroll
      for (int ni = 0; ni < 4; ++ni) {
        int r = bm + wr * 128 + mi * 16 + lr;
        int c = bn + wc * 64 + ni * 16 + kg * 4 - 2048;
        int bh2 = (r >> 11) * 16 + (c >> 6);
        int j = r & 2047;
        u16* vrow = VT + ((size_t)bh2 * 64 + (c & 63)) * 2048 + j;
        f32x4 a = acc[mi][ni];
#pragma unroll
        for (int rr = 0; rr < 4; ++rr) vrow[(size_t)rr * 2048] = f2h(a[rr]);
      }
  } else {
    float scale = (bn < 1024) ? EKF : 1.0f;
#pragma unroll
    for (int mi = 0; mi < 8; ++mi)
#pragma unroll
      for (int ni = 0; ni < 4; ++ni) {
        int row = wr * 128 + mi * 16 + lr;
        u32 off = (u32)row * 256 + wc * 64 + (((ni * 4 + kg) ^ (lr & 6)) * 4);
        f32x4 a = acc[mi][ni];
        *(uint2*)((u16*)smem + off) =
            make_uint2(pack2(a[0] * scale, a[1] * scale), pack2(a[2] * scale, a[3] * scale));
      }
    __syncthreads();
#pragma unroll
    for (int i = 0; i < 16; ++i) {
      int row = i * 16 + (tid >> 5);
      int lc = tid & 31;
      int blk = lc >> 3, cc = lc & 7;
      uint4 v = *(const uint4*)((const u16*)smem + (u32)row * 256 + blk * 64 +
                                (((2 * cc) ^ (row & 6)) * 4));
      *(uint4*)(QK + (size_t)(bm + row) * 2048 + bn + blk * 64 + cc * 8) = v;
    }
  }
}

// ---------------- NEW: out-proj GEMM: 64x128 tiles, XCD-swizzled, dbuf prefetch ----
// out[4096,1024] fp32 = attn[4096,1024]bf16 @ woutT[1024,1024]bf16^T. 512 blocks
// (2/CU). XCD swizzle: xcd=b&7 owns M-panels [xcd*8, xcd*8+8) x all 8 N-tiles ->
// per-XCD fetch ~ A 1MB + B 2MB (vs 40MB unswizzled refetch measured in R0).
// Double-buffered: next K-tile's global_load_lds issued before current compute.
__global__ __launch_bounds__(256, 2) void gemm_out_kernel(const u16* __restrict__ A,
                                                          const u16* __restrict__ BT,
                                                          float* __restrict__ C) {
  __shared__ __attribute__((aligned(16))) u16 smem[2][12288];  // A 64x64 + B 128x64 per buf
  const int tid = threadIdx.x;
  const int wave = tid >> 6;
  const int lane = tid & 63;
  const int lr = lane & 15;
  const int kg = lane >> 4;
  const int lr7 = lr & 7;
  const int wm = (wave >> 1) * 32;  // M half (32 rows per wave)
  const int wn = (wave & 1) * 64;   // N half (64 cols per wave)

  const int b = blockIdx.x;
  const int xcd = b & 7, loc = b >> 3;           // loc 0..63
  const int bm = (xcd * 8 + (loc >> 3)) * 64;    // 64 M-panels, 8 per XCD
  const int bn = (loc & 7) * 128;                // 8 N-tiles

  const int sr = tid >> 3;                        // 0..31
  const int scg = ((tid & 7) ^ (sr & 7)) * 8;     // swizzled source col (u16)
  const u16* pa = A + (size_t)(bm + sr) * 1024 + scg;
  const u16* pb = BT + (size_t)(bn + sr) * 1024 + scg;
  const u32 lw = (u32)wave * 512;

  f32x4 acc[2][4];
#pragma unroll
  for (int i = 0; i < 2; ++i)
#pragma unroll
    for (int j = 0; j < 4; ++j) {
      f32x4 z = {0.f, 0.f, 0.f, 0.f};
      acc[i][j] = z;
    }

  {  // prologue: stage tile 0 into buffer 0
    u16* dA = smem[0];
    u16* dB = smem[0] + 4096;
#pragma unroll
    for (int i = 0; i < 2; ++i) gld_lds16(pa + (size_t)(i * 32) * 1024, dA + lw + i * 2048);
#pragma unroll
    for (int i = 0; i < 4; ++i) gld_lds16(pb + (size_t)(i * 32) * 1024, dB + lw + i * 2048);
  }

  for (int t = 0; t < 16; ++t) {
    __syncthreads();  // tile t's loads complete
    const u16* bA = smem[t & 1];
    const u16* bB = bA + 4096;
    if (t + 1 < 16) {  // issue next tile with a full compute-phase of lead
      u16* dA = smem[(t + 1) & 1];
      u16* dB = dA + 4096;
      const int k1 = (t + 1) * 64;
#pragma unroll
      for (int i = 0; i < 2; ++i) gld_lds16(pa + (size_t)(i * 32) * 1024 + k1, dA + lw + i * 2048);
#pragma unroll
      for (int i = 0; i < 4; ++i) gld_lds16(pb + (size_t)(i * 32) * 1024 + k1, dB + lw + i * 2048);
    }
#pragma unroll
    for (int kk = 0; kk < 2; ++kk) {
      const int ch = ((kk * 4 + kg) ^ lr7) * 8;
      bf16x8 af[2], bfr[4];
#pragma unroll
      for (int mi = 0; mi < 2; ++mi)
        af[mi] = *(const bf16x8*)(bA + (wm + mi * 16 + lr) * 64 + ch);
#pragma unroll
      for (int ni = 0; ni < 4; ++ni)
        bfr[ni] = *(const bf16x8*)(bB + (wn + ni * 16 + lr) * 64 + ch);
      __builtin_amdgcn_s_setprio(1);
#pragma unroll
      for (int mi = 0; mi < 2; ++mi)
#pragma unroll
        for (int ni = 0; ni < 4; ++ni)
          acc[mi][ni] = __builtin_amdgcn_mfma_f32_16x16x32_bf16(bfr[ni], af[mi], acc[mi][ni], 0, 0, 0);
      __builtin_amdgcn_s_setprio(0);
    }
  }

  // epilogue: stage fp32 [64][64] col-halves through LDS, coalesced float4 out
  float* buf = (float*)smem;
#pragma unroll
  for (int hc = 0; hc < 2; ++hc) {
    __syncthreads();
    if ((wave & 1) == hc) {
#pragma unroll
      for (int mi = 0; mi < 2; ++mi)
#pragma unroll
        for (int ni = 0; ni < 4; ++ni) {
          int row = wm + mi * 16 + lr;                 // 0..63 (two waves cover all)
          int cp = ((ni * 4 + kg) ^ lr) * 4;           // 16-chunk swizzle, key lr
          *(f32x4*)(buf + row * 64 + cp) = acc[mi][ni];
        }
    }
    __syncthreads();
#pragma unroll
    for (int i = 0; i < 4; ++i) {
      int row = i * 16 + (tid >> 4);
      int lc = tid & 15;
      float4 v = *(const float4*)(buf + row * 64 + ((lc ^ (row & 15)) * 4));
      *(float4*)(C + (size_t)(bm + row) * 1024 + bn + hc * 64 + lc * 4) = v;
    }
  }
}

// ---------------- MFMA flash attention (R1 config: 1024 blocks heavy-first) ------
// + T5 setprio around the PV MFMA cluster (m191: +4-7% on attn, independent blocks).
__global__ __launch_bounds__(256, 4) void attn_mfma_kernel(const u16* __restrict__ qk,
                                                           const u16* __restrict__ vt,
                                                           u16* __restrict__ out) {
  __shared__ __attribute__((aligned(16))) u16 sK[2][64 * 64];  // [j][d] swizzled
  __shared__ __attribute__((aligned(16))) u16 sV[2][64 * 64];  // [d][j] swizzled
  __shared__ __attribute__((aligned(16))) u16 sP[4][16 * 64];  // [q][j] 8B-swizzled

  const int tid = threadIdx.x;
  const int wave = tid >> 6;
  const int lane = tid & 63;
  const int lr = lane & 15;  // q col (B), j/d row (A)
  const int kg = lane >> 4;  // k-group / row-quad
  const int l7 = lr & 7;

  int idx = blockIdx.x;
  int qi = 31 - (idx >> 5);  // heavy q-tiles first
  int bh = idx & 31;
  int b = bh >> 4, h = bh & 15;
  int q0 = qi * 64;

  const u16* qbase = qk + (size_t)b * 2048 * 2048 + h * 64;
  const u16* kbase = qbase + 1024;
  const u16* vbase = vt + (size_t)bh * 64 * 2048;
  u16* obase = out + (size_t)b * 2048 * 1024 + h * 64;

  const int sra = wave * 16 + (lane >> 3);
  const int srb = sra + 8;
  const int sc = lane & 7;
  const u32 koffA = (u32)sra * 2048 + (u32)((sc ^ (sra & 7)) * 8);
  const u32 koffB = (u32)srb * 2048 + (u32)((sc ^ (srb & 7)) * 8);
  const u32 ldsA = (wave * 2 + 0) * 512;
  const u32 ldsB = (wave * 2 + 1) * 512;

  const int qcol = q0 + wave * 16 + lr;
  bf16x8 qf0, qf1;
  {
    const u16* qrow = qbase + (size_t)qcol * 2048;
    qf0 = *(const bf16x8*)(qrow + kg * 8);
    qf1 = *(const bf16x8*)(qrow + 32 + kg * 8);
  }

  const u32 ka0 = (u32)(lr * 64 + ((kg ^ l7) * 8));
  const u32 ka1 = (u32)(lr * 64 + (((4 + kg) ^ l7) * 8));
  u16* const sPw = sP[wave];
  const u32 pr0 = (u32)(lr * 64 + (((kg * 2) ^ (l7 << 1)) * 4));
  const u32 pr1 = (u32)(lr * 64 + (((8 + kg * 2) ^ (l7 << 1)) * 4));

  f32x4 oacc[4];
#pragma unroll
  for (int i = 0; i < 4; ++i) {
    f32x4 z = {0.f, 0.f, 0.f, 0.f};
    oacc[i] = z;
  }
  float lsum = 0.f;

  const int nrounds = qi + 1;
  gld_lds16(kbase + koffA, sK[0] + ldsA);
  gld_lds16(kbase + koffB, sK[0] + ldsB);
  gld_lds16(vbase + koffA, sV[0] + ldsA);
  gld_lds16(vbase + koffB, sV[0] + ldsB);
  __syncthreads();

  for (int t = 0; t < nrounds; ++t) {
    if (t + 1 < nrounds) {
      int j1 = (t + 1) * 64;
      u16* dK = sK[(t + 1) & 1];
      u16* dV = sV[(t + 1) & 1];
      gld_lds16(kbase + (size_t)j1 * 2048 + koffA, dK + ldsA);
      gld_lds16(kbase + (size_t)j1 * 2048 + koffB, dK + ldsB);
      gld_lds16(vbase + j1 + koffA, dV + ldsA);
      gld_lds16(vbase + j1 + koffB, dV + ldsB);
    }
    const u16* sKb = sK[t & 1];
    const u16* sVb = sV[t & 1];
    const bool diag = (t == qi);

#pragma unroll
    for (int jt = 0; jt < 4; ++jt) {
      u16* pw = sPw + lr * 64 + (((jt * 4 + kg) ^ (l7 << 1)) * 4);
      if (!diag || jt <= wave) {
        bf16x8 kf0 = *(const bf16x8*)(sKb + jt * 1024 + ka0);
        bf16x8 kf1 = *(const bf16x8*)(sKb + jt * 1024 + ka1);
        f32x4 c = {0.f, 0.f, 0.f, 0.f};
        c = __builtin_amdgcn_mfma_f32_16x16x32_bf16(kf0, qf0, c, 0, 0, 0);
        c = __builtin_amdgcn_mfma_f32_16x16x32_bf16(kf1, qf1, c, 0, 0, 0);
        float p0 = exp2f(c[0]);
        float p1 = exp2f(c[1]);
        float p2 = exp2f(c[2]);
        float p3 = exp2f(c[3]);
        if (diag && jt == wave) {
          int jr = kg * 4;
          p0 = (jr + 0 <= lr) ? p0 : 0.f;
          p1 = (jr + 1 <= lr) ? p1 : 0.f;
          p2 = (jr + 2 <= lr) ? p2 : 0.f;
          p3 = (jr + 3 <= lr) ? p3 : 0.f;
        }
        lsum += (p0 + p1) + (p2 + p3);
        *(uint2*)pw = make_uint2(pkf16(p0, p1), pkf16(p2, p3));
      } else {
        *(uint2*)pw = make_uint2(0u, 0u);
      }
    }

    asm volatile("" ::: "memory");  // P writes precede P-frag reads (same wave)

    f16x8 pf0 = *(const f16x8*)(sPw + pr0);
    f16x8 pf1 = *(const f16x8*)(sPw + pr1);
    __builtin_amdgcn_s_setprio(1);
#pragma unroll
    for (int dt = 0; dt < 4; ++dt) {
      f16x8 vf0 = *(const f16x8*)(sVb + dt * 1024 + ka0);
      f16x8 vf1 = *(const f16x8*)(sVb + dt * 1024 + ka1);
      oacc[dt] = __builtin_amdgcn_mfma_f32_16x16x32_f16(vf0, pf0, oacc[dt], 0, 0, 0);
      oacc[dt] = __builtin_amdgcn_mfma_f32_16x16x32_f16(vf1, pf1, oacc[dt], 0, 0, 0);
    }
    __builtin_amdgcn_s_setprio(0);
    __syncthreads();
  }

  lsum += __shfl_xor(lsum, 16);
  lsum += __shfl_xor(lsum, 32);
  float inv = 1.0f / lsum;

  u16* orow = obase + (size_t)qcol * 1024;
#pragma unroll
  for (int dt = 0; dt < 4; ++dt) {
    uint2 o2 = make_uint2(pack2(oacc[dt][0] * inv, oacc[dt][1] * inv),
                          pack2(oacc[dt][2] * inv, oacc[dt][3] * inv));
    *(uint2*)(orow + dt * 16 + kg * 4) = o2;
  }
}

// ---------------- launch ----------------
extern "C" void kernel_launch(void* const* d_in, const int* in_sizes, int n_in,
                              void* d_out, int out_size, void* d_ws, size_t ws_size,
                              hipStream_t stream) {
  const float* x = (const float*)d_in[0];      // [2,2048,1024]
  const float* w_qkv = (const float*)d_in[1];  // [1024,3072]
  const float* w_out = (const float*)d_in[2];  // [1024,1024]
  float* out = (float*)d_out;                  // [2,2048,1024] fp32

  char* ws = (char*)d_ws;
  u16* xb    = (u16*)(ws);                //  8 MB: x bf16 [4096,1024]
  u16* wqkvT = (u16*)(ws + (8u << 20));   //  6 MB: w_qkv^T bf16 [3072,1024]
  u16* woutT = (u16*)(ws + (14u << 20));  //  2 MB: w_out^T bf16 [1024,1024]
  u16* qkb   = (u16*)(ws + (16u << 20));  // 16 MB: q|k bf16 [4096,2048]
  u16* vtb   = (u16*)(ws + (32u << 20));  //  8 MB: V^T f16 [32,64,2048]
  u16* attn  = (u16*)(ws + (40u << 20));  //  8 MB: attn out bf16 [4096,1024]

  prepass_kernel<<<5120, 256, 0, stream>>>(x, w_qkv, w_out, xb, wqkvT, woutT);

  gemm_qkv256_kernel<<<192, 512, 0, stream>>>(xb, wqkvT, qkb, vtb);

  attn_mfma_kernel<<<1024, 256, 0, stream>>>(qkb, vtb, attn);

  gemm_out_kernel<<<512, 256, 0, stream>>>(attn, woutT, out);
}